// Round 1
// baseline (10760.672 us; speedup 1.0000x reference)
//
#include <hip/hip_runtime.h>
#include <stdint.h>
#include <math.h>

#define B_ 64
#define S_ 512
#define I_ 128
#define H_ 2048
#define O_ 128
#define NWG 128
#define COLS 16
#define NTHREADS 256
#define SLAB (B_ * H_)      /* 131072 elements per h snapshot */
#define WPAD 2056           /* 2048 + 8 bf16 pad -> +4 banks per row */
#define IPAD 136            /* 128 + 8 */

typedef __attribute__((ext_vector_type(8))) __bf16 bf16x8;
typedef __attribute__((ext_vector_type(4))) float floatx4;

__device__ __forceinline__ unsigned short f2bf(float f) {
    unsigned u = __float_as_uint(f);
    unsigned r = u + 0x7fffu + ((u >> 16) & 1u);   // RNE
    return (unsigned short)(r >> 16);
}
__device__ __forceinline__ float bf2f(unsigned short h) {
    return __uint_as_float(((unsigned)h) << 16);
}

// ---- prep kernels -------------------------------------------------------
__global__ void k_wsplit(const float* __restrict__ whh, const float* __restrict__ mask,
                         unsigned short* __restrict__ hi, unsigned short* __restrict__ lo, int n) {
    int i = blockIdx.x * blockDim.x + threadIdx.x;
    int stride = gridDim.x * blockDim.x;
    for (; i < n; i += stride) {
        float w = whh[i] * mask[i];
        unsigned short h = f2bf(w);
        hi[i] = h;
        lo[i] = f2bf(w - bf2f(h));
    }
}
__global__ void k_split(const float* __restrict__ src,
                        unsigned short* __restrict__ hi, unsigned short* __restrict__ lo, int n) {
    int i = blockIdx.x * blockDim.x + threadIdx.x;
    int stride = gridDim.x * blockDim.x;
    for (; i < n; i += stride) {
        float w = src[i];
        unsigned short h = f2bf(w);
        hi[i] = h;
        lo[i] = f2bf(w - bf2f(h));
    }
}
__global__ void k_cast(const float* __restrict__ src, unsigned short* __restrict__ dst, int n) {
    int i = blockIdx.x * blockDim.x + threadIdx.x;
    int stride = gridDim.x * blockDim.x;
    for (; i < n; i += stride) dst[i] = f2bf(src[i]);
}

// ---- persistent recurrence kernel --------------------------------------
// grid = 128 WGs x 256 threads, 1 WG/CU (LDS-bound). WG wg owns output
// columns [wg*16, wg*16+16). Wm hi/lo slice resident in LDS for all 512
// steps. Split-K over 4 waves (512 k each), LDS reduction, device-scope
// per-step counter barrier (release add + relaxed agent spin + acquire).
__global__ __launch_bounds__(NTHREADS) void k_rnn(
    const unsigned short* __restrict__ whi, const unsigned short* __restrict__ wlo,
    const unsigned short* __restrict__ wihh, const unsigned short* __restrict__ wihl,
    const unsigned short* __restrict__ xbf, const float* __restrict__ bih,
    unsigned short* hs, unsigned int* ctr)
{
    extern __shared__ char smem[];
    unsigned short* sWhi  = (unsigned short*)smem;           // 16*2056
    unsigned short* sWlo  = sWhi + COLS * WPAD;              // 16*2056
    unsigned short* sWihH = sWlo + COLS * WPAD;              // 16*136
    unsigned short* sWihL = sWihH + COLS * IPAD;             // 16*136
    float* sRed = (float*)(sWihL + COLS * IPAD);             // 4*64*16 f32
    float* sBih = sRed + 4 * 64 * 16;                        // 16 f32

    const int tid = threadIdx.x;
    const int wg  = blockIdx.x;
    const int j0  = wg * COLS;
    const int w   = tid >> 6;
    const int lane = tid & 63;
    const int q   = lane >> 4;
    const int nn  = lane & 15;

    // stage Wm hi/lo slice (16 rows x 2048) into LDS, padded rows
    for (int idx = tid; idx < COLS * 256; idx += NTHREADS) {
        int r = idx >> 8, c = (idx & 255) * 8;
        *(uint4*)&sWhi[r * WPAD + c] = *(const uint4*)&whi[(size_t)(j0 + r) * H_ + c];
        *(uint4*)&sWlo[r * WPAD + c] = *(const uint4*)&wlo[(size_t)(j0 + r) * H_ + c];
    }
    for (int idx = tid; idx < COLS * 16; idx += NTHREADS) {
        int r = idx >> 4, c = (idx & 15) * 8;
        *(uint4*)&sWihH[r * IPAD + c] = *(const uint4*)&wihh[(size_t)(j0 + r) * I_ + c];
        *(uint4*)&sWihL[r * IPAD + c] = *(const uint4*)&wihl[(size_t)(j0 + r) * I_ + c];
    }
    if (tid < COLS) sBih[tid] = bih[j0 + tid];
    __syncthreads();

    const int kb  = w * 512;   // this wave's k range in H
    const int xkb = w * 32;    // this wave's k range in I
    // Wih B-fragments are t-invariant: load once
    const bf16x8 bxh = *(const bf16x8*)&sWihH[nn * IPAD + xkb + q * 8];
    const bf16x8 bxl = *(const bf16x8*)&sWihL[nn * IPAD + xkb + q * 8];

#pragma unroll 1
    for (int t = 0; t < S_; ++t) {
        const unsigned short* hp = hs + (size_t)t * SLAB;
        floatx4 a0 = {0.f, 0.f, 0.f, 0.f}, a1 = a0, a2 = a0, a3 = a0;

        // fused input projection: acc += x_t[b, xkb..] * Wih[j, xkb..]^T
        {
            const size_t xoff = (size_t)t * I_ + xkb + q * 8;
            bf16x8 x0 = *(const bf16x8*)&xbf[(size_t)(nn)      * (S_ * I_) + xoff];
            bf16x8 x1 = *(const bf16x8*)&xbf[(size_t)(16 + nn) * (S_ * I_) + xoff];
            bf16x8 x2 = *(const bf16x8*)&xbf[(size_t)(32 + nn) * (S_ * I_) + xoff];
            bf16x8 x3 = *(const bf16x8*)&xbf[(size_t)(48 + nn) * (S_ * I_) + xoff];
            a0 = __builtin_amdgcn_mfma_f32_16x16x32_bf16(x0, bxh, a0, 0, 0, 0);
            a1 = __builtin_amdgcn_mfma_f32_16x16x32_bf16(x1, bxh, a1, 0, 0, 0);
            a2 = __builtin_amdgcn_mfma_f32_16x16x32_bf16(x2, bxh, a2, 0, 0, 0);
            a3 = __builtin_amdgcn_mfma_f32_16x16x32_bf16(x3, bxh, a3, 0, 0, 0);
            a0 = __builtin_amdgcn_mfma_f32_16x16x32_bf16(x0, bxl, a0, 0, 0, 0);
            a1 = __builtin_amdgcn_mfma_f32_16x16x32_bf16(x1, bxl, a1, 0, 0, 0);
            a2 = __builtin_amdgcn_mfma_f32_16x16x32_bf16(x2, bxl, a2, 0, 0, 0);
            a3 = __builtin_amdgcn_mfma_f32_16x16x32_bf16(x3, bxl, a3, 0, 0, 0);
        }

        // recurrent part: this wave's 512-wide k slice, 16 MFMA k-steps
#pragma unroll 4
        for (int ks = 0; ks < 16; ++ks) {
            const int kk = kb + ks * 32 + q * 8;
            bf16x8 bh = *(const bf16x8*)&sWhi[nn * WPAD + kk];
            bf16x8 bl = *(const bf16x8*)&sWlo[nn * WPAD + kk];
            bf16x8 h0 = *(const bf16x8*)&hp[(size_t)(nn)      * H_ + kk];
            bf16x8 h1 = *(const bf16x8*)&hp[(size_t)(16 + nn) * H_ + kk];
            bf16x8 h2 = *(const bf16x8*)&hp[(size_t)(32 + nn) * H_ + kk];
            bf16x8 h3 = *(const bf16x8*)&hp[(size_t)(48 + nn) * H_ + kk];
            a0 = __builtin_amdgcn_mfma_f32_16x16x32_bf16(h0, bh, a0, 0, 0, 0);
            a1 = __builtin_amdgcn_mfma_f32_16x16x32_bf16(h1, bh, a1, 0, 0, 0);
            a2 = __builtin_amdgcn_mfma_f32_16x16x32_bf16(h2, bh, a2, 0, 0, 0);
            a3 = __builtin_amdgcn_mfma_f32_16x16x32_bf16(h3, bh, a3, 0, 0, 0);
            a0 = __builtin_amdgcn_mfma_f32_16x16x32_bf16(h0, bl, a0, 0, 0, 0);
            a1 = __builtin_amdgcn_mfma_f32_16x16x32_bf16(h1, bl, a1, 0, 0, 0);
            a2 = __builtin_amdgcn_mfma_f32_16x16x32_bf16(h2, bl, a2, 0, 0, 0);
            a3 = __builtin_amdgcn_mfma_f32_16x16x32_bf16(h3, bl, a3, 0, 0, 0);
        }

        // wave partials -> LDS.  C layout: row m = q*4+reg, col = nn
#pragma unroll
        for (int r = 0; r < 4; ++r) {
            sRed[(w * 64 +      q * 4 + r) * 16 + nn] = a0[r];
            sRed[(w * 64 + 16 + q * 4 + r) * 16 + nn] = a1[r];
            sRed[(w * 64 + 32 + q * 4 + r) * 16 + nn] = a2[r];
            sRed[(w * 64 + 48 + q * 4 + r) * 16 + nn] = a3[r];
        }
        __syncthreads();

        // reduce 4 waves, +bih, tanh, pack bf16, store h slice
        {
            const int m  = tid >> 2;          // batch index 0..63
            const int n0 = (tid & 3) * 4;     // local col 0,4,8,12
            floatx4 s = *(const floatx4*)&sRed[(0 * 64 + m) * 16 + n0];
            s += *(const floatx4*)&sRed[(1 * 64 + m) * 16 + n0];
            s += *(const floatx4*)&sRed[(2 * 64 + m) * 16 + n0];
            s += *(const floatx4*)&sRed[(3 * 64 + m) * 16 + n0];
            ushort4 pk = make_ushort4(
                f2bf(tanhf(s[0] + sBih[n0 + 0])),
                f2bf(tanhf(s[1] + sBih[n0 + 1])),
                f2bf(tanhf(s[2] + sBih[n0 + 2])),
                f2bf(tanhf(s[3] + sBih[n0 + 3])));
            *(ushort4*)&hs[(size_t)(t + 1) * SLAB + (size_t)m * H_ + j0 + n0] = pk;
        }
        __syncthreads();   // drains each wave's vmcnt -> stores are in L2

        // device-scope barrier: one monotonic counter per step (no reset)
        if (tid == 0) {
            __hip_atomic_fetch_add(&ctr[t], 1u, __ATOMIC_RELEASE, __HIP_MEMORY_SCOPE_AGENT);
            while (__hip_atomic_load(&ctr[t], __ATOMIC_RELAXED, __HIP_MEMORY_SCOPE_AGENT) < (unsigned)NWG)
                __builtin_amdgcn_s_sleep(2);
        }
        __syncthreads();
        __threadfence();   // acquire: invalidate stale L1/L2 before reading h(t)
    }
}

// ---- output projection: out[b,t,o] = hs[t+1][b,:] . Who[o,:] + bho ------
__global__ __launch_bounds__(NTHREADS) void k_out(
    const unsigned short* __restrict__ hflat, const unsigned short* __restrict__ who,
    const float* __restrict__ bho, float* __restrict__ out)
{
    const int tid = threadIdx.x;
    const int w = tid >> 6, lane = tid & 63, q = lane >> 4, nn = lane & 15;
    const size_t r0 = ((size_t)blockIdx.x * 4 + w) * 16;   // row = t*64+b
    floatx4 acc[8];
#pragma unroll
    for (int i = 0; i < 8; ++i) acc[i] = floatx4{0.f, 0.f, 0.f, 0.f};
    for (int ks = 0; ks < 64; ++ks) {
        const int kk = ks * 32 + q * 8;
        bf16x8 a = *(const bf16x8*)&hflat[(r0 + nn) * H_ + kk];
#pragma unroll
        for (int nt = 0; nt < 8; ++nt) {
            bf16x8 b = *(const bf16x8*)&who[(size_t)(nt * 16 + nn) * H_ + kk];
            acc[nt] = __builtin_amdgcn_mfma_f32_16x16x32_bf16(a, b, acc[nt], 0, 0, 0);
        }
    }
#pragma unroll
    for (int nt = 0; nt < 8; ++nt) {
#pragma unroll
        for (int r = 0; r < 4; ++r) {
            size_t rr = r0 + q * 4 + r;
            int t = (int)(rr >> 6), b = (int)(rr & 63);
            int o = nt * 16 + nn;
            out[(size_t)b * (S_ * O_) + (size_t)t * O_ + o] = acc[nt][r] + bho[o];
        }
    }
}

// ---- host ----------------------------------------------------------------
extern "C" void kernel_launch(void* const* d_in, const int* in_sizes, int n_in,
                              void* d_out, int out_size, void* d_ws, size_t ws_size,
                              hipStream_t stream) {
    const float* x    = (const float*)d_in[0];
    const float* Wih  = (const float*)d_in[1];
    const float* bih  = (const float*)d_in[2];
    const float* Whh  = (const float*)d_in[3];
    const float* Who  = (const float*)d_in[4];
    const float* bho  = (const float*)d_in[5];
    const float* mask = (const float*)d_in[6];
    float* out = (float*)d_out;

    char* ws = (char*)d_ws;
    constexpr size_t CTR_OFF  = 0;
    constexpr size_t HS_OFF   = 4096;
    constexpr size_t HS_BYTES = (size_t)(S_ + 1) * SLAB * 2;
    constexpr size_t WHI_OFF  = HS_OFF + HS_BYTES;
    constexpr size_t WLO_OFF  = WHI_OFF + (size_t)H_ * H_ * 2;
    constexpr size_t XBF_OFF  = WLO_OFF + (size_t)H_ * H_ * 2;
    constexpr size_t WIHH_OFF = XBF_OFF + (size_t)B_ * S_ * I_ * 2;
    constexpr size_t WIHL_OFF = WIHH_OFF + (size_t)H_ * I_ * 2;
    constexpr size_t WHO_OFF  = WIHL_OFF + (size_t)H_ * I_ * 2;
    constexpr size_t WS_NEED  = WHO_OFF + (size_t)O_ * H_ * 2;
    if (ws_size < WS_NEED) return;   // workspace too small: fail loudly via mismatch

    unsigned int*   ctr   = (unsigned int*)(ws + CTR_OFF);
    unsigned short* hs    = (unsigned short*)(ws + HS_OFF);
    unsigned short* whi   = (unsigned short*)(ws + WHI_OFF);
    unsigned short* wlo   = (unsigned short*)(ws + WLO_OFF);
    unsigned short* xbf   = (unsigned short*)(ws + XBF_OFF);
    unsigned short* wihh  = (unsigned short*)(ws + WIHH_OFF);
    unsigned short* wihl  = (unsigned short*)(ws + WIHL_OFF);
    unsigned short* whobf = (unsigned short*)(ws + WHO_OFF);

    hipMemsetAsync(ctr, 0, 4096, stream);                 // step counters
    hipMemsetAsync(hs, 0, (size_t)SLAB * 2, stream);      // h_{-1} = 0

    k_wsplit<<<1024, 256, 0, stream>>>(Whh, mask, whi, wlo, H_ * H_);
    k_split <<<256, 256, 0, stream>>>(Wih, wihh, wihl, H_ * I_);
    k_cast  <<<256, 256, 0, stream>>>(Who, whobf, O_ * H_);
    k_cast  <<<1024, 256, 0, stream>>>(x, xbf, B_ * S_ * I_);

    constexpr int SMEM = (COLS * WPAD * 2 + COLS * IPAD * 2) * 2   // W slices bf16
                       + (4 * 64 * 16 + 16) * 4;                    // reduction + bih
    static_assert(SMEM <= 160 * 1024, "LDS budget");
    hipFuncSetAttribute((const void*)k_rnn, hipFuncAttributeMaxDynamicSharedMemorySize, SMEM);
    k_rnn<<<NWG, NTHREADS, SMEM, stream>>>(whi, wlo, wihh, wihl, xbf, bih, hs, ctr);
    k_out<<<512, NTHREADS, 0, stream>>>(hs + SLAB, whobf, bho, out);
}

// Round 2
// 5158.212 us; speedup vs baseline: 2.0861x; 2.0861x over previous
//
#include <hip/hip_runtime.h>
#include <stdint.h>
#include <math.h>

#define B_ 64
#define S_ 512
#define I_ 128
#define H_ 2048
#define O_ 128
#define NWG 128
#define COLS 16
#define NTHREADS 256
#define SLAB (B_ * H_)      /* 131072 elements per h snapshot */
#define WPAD 2056           /* 2048 + 8 bf16 pad */
#define IPAD 136            /* 128 + 8 */
#define RSTR 20             /* sRed row stride in floats: 2-way max bank aliasing */

typedef __attribute__((ext_vector_type(8))) __bf16 bf16x8;
typedef __attribute__((ext_vector_type(4))) float floatx4;

__device__ __forceinline__ unsigned short f2bf(float f) {
    unsigned u = __float_as_uint(f);
    unsigned r = u + 0x7fffu + ((u >> 16) & 1u);   // RNE
    return (unsigned short)(r >> 16);
}
__device__ __forceinline__ float bf2f(unsigned short h) {
    return __uint_as_float(((unsigned)h) << 16);
}
// tanh(x) = 1 - 2/(e^{2x}+1); v_exp+v_rcp, err ~1e-6 << bf16 noise.
// e->inf: rcp(inf)=0 -> 1; e->0: -> -1. Correct saturation.
__device__ __forceinline__ float fast_tanh(float x) {
    float e = __expf(2.0f * x);
    return 1.0f - 2.0f * __builtin_amdgcn_rcpf(e + 1.0f);
}

// ---- prep kernels -------------------------------------------------------
__global__ void k_wsplit(const float* __restrict__ whh, const float* __restrict__ mask,
                         unsigned short* __restrict__ hi, unsigned short* __restrict__ lo, int n) {
    int i = blockIdx.x * blockDim.x + threadIdx.x;
    int stride = gridDim.x * blockDim.x;
    for (; i < n; i += stride) {
        float w = whh[i] * mask[i];
        unsigned short h = f2bf(w);
        hi[i] = h;
        lo[i] = f2bf(w - bf2f(h));
    }
}
__global__ void k_split(const float* __restrict__ src,
                        unsigned short* __restrict__ hi, unsigned short* __restrict__ lo, int n) {
    int i = blockIdx.x * blockDim.x + threadIdx.x;
    int stride = gridDim.x * blockDim.x;
    for (; i < n; i += stride) {
        float w = src[i];
        unsigned short h = f2bf(w);
        hi[i] = h;
        lo[i] = f2bf(w - bf2f(h));
    }
}
__global__ void k_cast(const float* __restrict__ src, unsigned short* __restrict__ dst, int n) {
    int i = blockIdx.x * blockDim.x + threadIdx.x;
    int stride = gridDim.x * blockDim.x;
    for (; i < n; i += stride) dst[i] = f2bf(src[i]);
}

// ---- persistent recurrence kernel --------------------------------------
// 128 WGs x 256 thr. WG owns 16 output cols; Wm hi/lo slice in LDS all run.
// Per-step sync: h stores are agent-scope relaxed atomic stores (sc1
// write-through to MALL); __syncthreads drains vmcnt => release without any
// buffer_wbl2/buffer_inv. Two-level barrier: 8 groups (blockIdx>>4) of 16.
// Arrive at end of step t; wait at start of step t+1 AFTER the h-independent
// x-projection MFMAs (overlap). All barrier ops relaxed AGENT atomics on
// monotonic per-step slots (no reset, no fences).
__global__ __launch_bounds__(NTHREADS) void k_rnn(
    const unsigned short* __restrict__ whi, const unsigned short* __restrict__ wlo,
    const unsigned short* __restrict__ wihh, const unsigned short* __restrict__ wihl,
    const unsigned short* __restrict__ xbf, const float* __restrict__ bih,
    unsigned short* hs, unsigned int* bar)
{
    extern __shared__ char smem[];
    unsigned short* sWhi  = (unsigned short*)smem;           // 16*2056
    unsigned short* sWlo  = sWhi + COLS * WPAD;              // 16*2056
    unsigned short* sWihH = sWlo + COLS * WPAD;              // 16*136
    unsigned short* sWihL = sWihH + COLS * IPAD;             // 16*136
    float* sRed = (float*)(sWihL + COLS * IPAD);             // 256*RSTR f32
    float* sBih = sRed + 4 * 64 * RSTR;                      // 16 f32

    const int tid = threadIdx.x;
    const int wg  = blockIdx.x;
    const int j0  = wg * COLS;
    const int w   = tid >> 6;
    const int lane = tid & 63;
    const int q   = lane >> 4;
    const int nn  = lane & 15;

    const int grp = wg >> 4;                        // 0..7
    const bool isLeaderWG = ((wg & 15) == 0);
    unsigned int* const my_arr = bar + grp * S_;           // group arrivals
    unsigned int* const my_go  = bar + (8 + grp) * S_;     // group go flags
    unsigned int* const gctr   = bar + 16 * S_;            // 8 leaders/step

    // stage Wm hi/lo slice (16 rows x 2048) into LDS, padded rows
    for (int idx = tid; idx < COLS * 256; idx += NTHREADS) {
        int r = idx >> 8, c = (idx & 255) * 8;
        *(uint4*)&sWhi[r * WPAD + c] = *(const uint4*)&whi[(size_t)(j0 + r) * H_ + c];
        *(uint4*)&sWlo[r * WPAD + c] = *(const uint4*)&wlo[(size_t)(j0 + r) * H_ + c];
    }
    for (int idx = tid; idx < COLS * 16; idx += NTHREADS) {
        int r = idx >> 4, c = (idx & 15) * 8;
        *(uint4*)&sWihH[r * IPAD + c] = *(const uint4*)&wihh[(size_t)(j0 + r) * I_ + c];
        *(uint4*)&sWihL[r * IPAD + c] = *(const uint4*)&wihl[(size_t)(j0 + r) * I_ + c];
    }
    if (tid < COLS) sBih[tid] = bih[j0 + tid];
    __syncthreads();

    const int kb  = w * 512;   // this wave's k range in H
    const int xkb = w * 32;    // this wave's k range in I
    const bf16x8 bxh = *(const bf16x8*)&sWihH[nn * IPAD + xkb + q * 8];
    const bf16x8 bxl = *(const bf16x8*)&sWihL[nn * IPAD + xkb + q * 8];

#pragma unroll 1
    for (int t = 0; t < S_; ++t) {
        const unsigned short* hp = hs + (size_t)t * SLAB;
        floatx4 a0 = {0.f, 0.f, 0.f, 0.f}, a1 = a0, a2 = a0, a3 = a0;

        // h-independent x-projection first (overlaps the barrier wait)
        {
            const size_t xoff = (size_t)t * I_ + xkb + q * 8;
            bf16x8 x0 = *(const bf16x8*)&xbf[(size_t)(nn)      * (S_ * I_) + xoff];
            bf16x8 x1 = *(const bf16x8*)&xbf[(size_t)(16 + nn) * (S_ * I_) + xoff];
            bf16x8 x2 = *(const bf16x8*)&xbf[(size_t)(32 + nn) * (S_ * I_) + xoff];
            bf16x8 x3 = *(const bf16x8*)&xbf[(size_t)(48 + nn) * (S_ * I_) + xoff];
            a0 = __builtin_amdgcn_mfma_f32_16x16x32_bf16(x0, bxh, a0, 0, 0, 0);
            a1 = __builtin_amdgcn_mfma_f32_16x16x32_bf16(x1, bxh, a1, 0, 0, 0);
            a2 = __builtin_amdgcn_mfma_f32_16x16x32_bf16(x2, bxh, a2, 0, 0, 0);
            a3 = __builtin_amdgcn_mfma_f32_16x16x32_bf16(x3, bxh, a3, 0, 0, 0);
            a0 = __builtin_amdgcn_mfma_f32_16x16x32_bf16(x0, bxl, a0, 0, 0, 0);
            a1 = __builtin_amdgcn_mfma_f32_16x16x32_bf16(x1, bxl, a1, 0, 0, 0);
            a2 = __builtin_amdgcn_mfma_f32_16x16x32_bf16(x2, bxl, a2, 0, 0, 0);
            a3 = __builtin_amdgcn_mfma_f32_16x16x32_bf16(x3, bxl, a3, 0, 0, 0);
        }

        // wait for h(t) (barrier instance t-1); t=0 reads memset zeros
        if (t > 0) {
            if (tid == 0) {
                if (!isLeaderWG) {
                    while (__hip_atomic_load(&my_go[t - 1], __ATOMIC_RELAXED,
                                             __HIP_MEMORY_SCOPE_AGENT) == 0u)
                        __builtin_amdgcn_s_sleep(1);
                } else {
                    while (__hip_atomic_load(&my_arr[t - 1], __ATOMIC_RELAXED,
                                             __HIP_MEMORY_SCOPE_AGENT) < 16u)
                        __builtin_amdgcn_s_sleep(1);
                    __hip_atomic_fetch_add(&gctr[t - 1], 1u, __ATOMIC_RELAXED,
                                           __HIP_MEMORY_SCOPE_AGENT);
                    while (__hip_atomic_load(&gctr[t - 1], __ATOMIC_RELAXED,
                                             __HIP_MEMORY_SCOPE_AGENT) < 8u)
                        __builtin_amdgcn_s_sleep(1);
                    __hip_atomic_store(&my_go[t - 1], 1u, __ATOMIC_RELAXED,
                                       __HIP_MEMORY_SCOPE_AGENT);
                }
            }
            __syncthreads();
        }

        // recurrent part: this wave's 512-wide k slice, 16 MFMA k-steps
#pragma unroll 4
        for (int ks = 0; ks < 16; ++ks) {
            const int kk = kb + ks * 32 + q * 8;
            bf16x8 bh = *(const bf16x8*)&sWhi[nn * WPAD + kk];
            bf16x8 bl = *(const bf16x8*)&sWlo[nn * WPAD + kk];
            bf16x8 h0 = *(const bf16x8*)&hp[(size_t)(nn)      * H_ + kk];
            bf16x8 h1 = *(const bf16x8*)&hp[(size_t)(16 + nn) * H_ + kk];
            bf16x8 h2 = *(const bf16x8*)&hp[(size_t)(32 + nn) * H_ + kk];
            bf16x8 h3 = *(const bf16x8*)&hp[(size_t)(48 + nn) * H_ + kk];
            a0 = __builtin_amdgcn_mfma_f32_16x16x32_bf16(h0, bh, a0, 0, 0, 0);
            a1 = __builtin_amdgcn_mfma_f32_16x16x32_bf16(h1, bh, a1, 0, 0, 0);
            a2 = __builtin_amdgcn_mfma_f32_16x16x32_bf16(h2, bh, a2, 0, 0, 0);
            a3 = __builtin_amdgcn_mfma_f32_16x16x32_bf16(h3, bh, a3, 0, 0, 0);
            a0 = __builtin_amdgcn_mfma_f32_16x16x32_bf16(h0, bl, a0, 0, 0, 0);
            a1 = __builtin_amdgcn_mfma_f32_16x16x32_bf16(h1, bl, a1, 0, 0, 0);
            a2 = __builtin_amdgcn_mfma_f32_16x16x32_bf16(h2, bl, a2, 0, 0, 0);
            a3 = __builtin_amdgcn_mfma_f32_16x16x32_bf16(h3, bl, a3, 0, 0, 0);
        }

        // wave partials -> LDS. row = w*64 + sub*16 + q*4+r, stride RSTR
#pragma unroll
        for (int r = 0; r < 4; ++r) {
            sRed[(w * 64 +      q * 4 + r) * RSTR + nn] = a0[r];
            sRed[(w * 64 + 16 + q * 4 + r) * RSTR + nn] = a1[r];
            sRed[(w * 64 + 32 + q * 4 + r) * RSTR + nn] = a2[r];
            sRed[(w * 64 + 48 + q * 4 + r) * RSTR + nn] = a3[r];
        }
        __syncthreads();

        // reduce 4 waves, +bih, tanh, pack bf16, agent-scope store h slice
        {
            const int m  = tid >> 2;          // batch index 0..63
            const int n0 = (tid & 3) * 4;     // local col 0,4,8,12
            floatx4 s = *(const floatx4*)&sRed[(0 * 64 + m) * RSTR + n0];
            s += *(const floatx4*)&sRed[(1 * 64 + m) * RSTR + n0];
            s += *(const floatx4*)&sRed[(2 * 64 + m) * RSTR + n0];
            s += *(const floatx4*)&sRed[(3 * 64 + m) * RSTR + n0];
            union { ushort4 u4; unsigned long long u64; } cv;
            cv.u4 = make_ushort4(
                f2bf(fast_tanh(s[0] + sBih[n0 + 0])),
                f2bf(fast_tanh(s[1] + sBih[n0 + 1])),
                f2bf(fast_tanh(s[2] + sBih[n0 + 2])),
                f2bf(fast_tanh(s[3] + sBih[n0 + 3])));
            unsigned long long* dst = (unsigned long long*)
                &hs[(size_t)(t + 1) * SLAB + (size_t)m * H_ + j0 + n0];
            __hip_atomic_store(dst, cv.u64, __ATOMIC_RELAXED, __HIP_MEMORY_SCOPE_AGENT);
        }
        __syncthreads();   // vmcnt(0): sc1 stores acked at coherence point

        if (tid == 0)      // arrive (barrier instance t); wait happens next iter
            __hip_atomic_fetch_add(&my_arr[t], 1u, __ATOMIC_RELAXED,
                                   __HIP_MEMORY_SCOPE_AGENT);
    }
}

// ---- output projection: out[b,t,o] = hs[t+1][b,:] . Who[o,:] + bho ------
__global__ __launch_bounds__(NTHREADS) void k_out(
    const unsigned short* __restrict__ hflat, const unsigned short* __restrict__ who,
    const float* __restrict__ bho, float* __restrict__ out)
{
    const int tid = threadIdx.x;
    const int w = tid >> 6, lane = tid & 63, q = lane >> 4, nn = lane & 15;
    const size_t r0 = ((size_t)blockIdx.x * 4 + w) * 16;   // row = t*64+b
    floatx4 acc[8];
#pragma unroll
    for (int i = 0; i < 8; ++i) acc[i] = floatx4{0.f, 0.f, 0.f, 0.f};
    for (int ks = 0; ks < 64; ++ks) {
        const int kk = ks * 32 + q * 8;
        bf16x8 a = *(const bf16x8*)&hflat[(r0 + nn) * H_ + kk];
#pragma unroll
        for (int nt = 0; nt < 8; ++nt) {
            bf16x8 b = *(const bf16x8*)&who[(size_t)(nt * 16 + nn) * H_ + kk];
            acc[nt] = __builtin_amdgcn_mfma_f32_16x16x32_bf16(a, b, acc[nt], 0, 0, 0);
        }
    }
#pragma unroll
    for (int nt = 0; nt < 8; ++nt) {
#pragma unroll
        for (int r = 0; r < 4; ++r) {
            size_t rr = r0 + q * 4 + r;
            int t = (int)(rr >> 6), b = (int)(rr & 63);
            int o = nt * 16 + nn;
            out[(size_t)b * (S_ * O_) + (size_t)t * O_ + o] = acc[nt][r] + bho[o];
        }
    }
}

// ---- host ----------------------------------------------------------------
extern "C" void kernel_launch(void* const* d_in, const int* in_sizes, int n_in,
                              void* d_out, int out_size, void* d_ws, size_t ws_size,
                              hipStream_t stream) {
    const float* x    = (const float*)d_in[0];
    const float* Wih  = (const float*)d_in[1];
    const float* bih  = (const float*)d_in[2];
    const float* Whh  = (const float*)d_in[3];
    const float* Who  = (const float*)d_in[4];
    const float* bho  = (const float*)d_in[5];
    const float* mask = (const float*)d_in[6];
    float* out = (float*)d_out;

    char* ws = (char*)d_ws;
    // barrier region: [0,64K). arrivals 8*512, go 8*512, gctr 512 (monotonic)
    constexpr size_t BAR_OFF  = 0;
    constexpr size_t HS_OFF   = 65536;
    constexpr size_t HS_BYTES = (size_t)(S_ + 1) * SLAB * 2;
    constexpr size_t WHI_OFF  = HS_OFF + HS_BYTES;
    constexpr size_t WLO_OFF  = WHI_OFF + (size_t)H_ * H_ * 2;
    constexpr size_t XBF_OFF  = WLO_OFF + (size_t)H_ * H_ * 2;
    constexpr size_t WIHH_OFF = XBF_OFF + (size_t)B_ * S_ * I_ * 2;
    constexpr size_t WIHL_OFF = WIHH_OFF + (size_t)H_ * I_ * 2;
    constexpr size_t WHO_OFF  = WIHL_OFF + (size_t)H_ * I_ * 2;
    constexpr size_t WS_NEED  = WHO_OFF + (size_t)O_ * H_ * 2;
    if (ws_size < WS_NEED) return;

    unsigned int*   bar   = (unsigned int*)(ws + BAR_OFF);
    unsigned short* hs    = (unsigned short*)(ws + HS_OFF);
    unsigned short* whi   = (unsigned short*)(ws + WHI_OFF);
    unsigned short* wlo   = (unsigned short*)(ws + WLO_OFF);
    unsigned short* xbf   = (unsigned short*)(ws + XBF_OFF);
    unsigned short* wihh  = (unsigned short*)(ws + WIHH_OFF);
    unsigned short* wihl  = (unsigned short*)(ws + WIHL_OFF);
    unsigned short* whobf = (unsigned short*)(ws + WHO_OFF);

    hipMemsetAsync(bar, 0, 65536, stream);                // barrier slots
    hipMemsetAsync(hs, 0, (size_t)SLAB * 2, stream);      // h_{-1} = 0

    k_wsplit<<<1024, 256, 0, stream>>>(Whh, mask, whi, wlo, H_ * H_);
    k_split <<<256, 256, 0, stream>>>(Wih, wihh, wihl, H_ * I_);
    k_cast  <<<256, 256, 0, stream>>>(Who, whobf, O_ * H_);
    k_cast  <<<1024, 256, 0, stream>>>(x, xbf, B_ * S_ * I_);

    constexpr int SMEM = (COLS * WPAD * 2 + COLS * IPAD * 2) * 2   // W slices bf16
                       + (4 * 64 * RSTR + 16) * 4;                  // sRed + bih
    static_assert(SMEM <= 160 * 1024, "LDS budget");
    hipFuncSetAttribute((const void*)k_rnn, hipFuncAttributeMaxDynamicSharedMemorySize, SMEM);
    k_rnn<<<NWG, NTHREADS, SMEM, stream>>>(whi, wlo, wihh, wihl, xbf, bih, hs, bar);
    k_out<<<512, NTHREADS, 0, stream>>>(hs + SLAB, whobf, bho, out);
}

// Round 3
// 5089.538 us; speedup vs baseline: 2.1143x; 1.0135x over previous
//
#include <hip/hip_runtime.h>
#include <stdint.h>
#include <math.h>

#define B_ 64
#define S_ 512
#define I_ 128
#define H_ 2048
#define O_ 128
#define NWG 128
#define COLS 16
#define NTHREADS 256
#define SLAB (B_ * H_)      /* 131072 elements per h snapshot */
#define RSTR 20             /* sRed row stride in floats: 2-way max bank aliasing */

typedef __attribute__((ext_vector_type(8))) __bf16 bf16x8;
typedef __attribute__((ext_vector_type(4))) float floatx4;

__device__ __forceinline__ unsigned short f2bf(float f) {
    unsigned u = __float_as_uint(f);
    unsigned r = u + 0x7fffu + ((u >> 16) & 1u);   // RNE
    return (unsigned short)(r >> 16);
}
__device__ __forceinline__ float bf2f(unsigned short h) {
    return __uint_as_float(((unsigned)h) << 16);
}
// tanh(x) = 1 - 2/(e^{2x}+1); v_exp+v_rcp, err ~1e-6 << bf16 noise.
__device__ __forceinline__ float fast_tanh(float x) {
    float e = __expf(2.0f * x);
    return 1.0f - 2.0f * __builtin_amdgcn_rcpf(e + 1.0f);
}

// ---- prep kernels -------------------------------------------------------
__global__ void k_wsplit(const float* __restrict__ whh, const float* __restrict__ mask,
                         unsigned short* __restrict__ hi, unsigned short* __restrict__ lo, int n) {
    int i = blockIdx.x * blockDim.x + threadIdx.x;
    int stride = gridDim.x * blockDim.x;
    for (; i < n; i += stride) {
        float w = whh[i] * mask[i];
        unsigned short h = f2bf(w);
        hi[i] = h;
        lo[i] = f2bf(w - bf2f(h));
    }
}
__global__ void k_split(const float* __restrict__ src,
                        unsigned short* __restrict__ hi, unsigned short* __restrict__ lo, int n) {
    int i = blockIdx.x * blockDim.x + threadIdx.x;
    int stride = gridDim.x * blockDim.x;
    for (; i < n; i += stride) {
        float w = src[i];
        unsigned short h = f2bf(w);
        hi[i] = h;
        lo[i] = f2bf(w - bf2f(h));
    }
}
__global__ void k_cast(const float* __restrict__ src, unsigned short* __restrict__ dst, int n) {
    int i = blockIdx.x * blockDim.x + threadIdx.x;
    int stride = gridDim.x * blockDim.x;
    for (; i < n; i += stride) dst[i] = f2bf(src[i]);
}

// ---- persistent recurrence kernel --------------------------------------
// 128 WGs x 256 thr. WG owns 16 output cols. W hi/lo fragments live in
// REGISTERS (time-invariant, 128 VGPRs) - zero LDS reads in the K-loop.
// Publish: each wave stores its share of h(t+1) with agent-scope sc1
// stores, drains its own vmcnt, then +1 on the WG's per-step flag.
// Consume: each wave polls only the 32 producer flags covering its own
// K-slice (one 32-lane load + ballot). No hierarchical barrier, no
// release fences, no cache flushes anywhere. One __syncthreads per step
// (sRed handoff), sRed double-buffered by step parity.
__global__ __launch_bounds__(NTHREADS, 1) void k_rnn(
    const unsigned short* __restrict__ whi, const unsigned short* __restrict__ wlo,
    const unsigned short* __restrict__ wihh, const unsigned short* __restrict__ wihl,
    const unsigned short* __restrict__ xbf, const float* __restrict__ bih,
    unsigned short* hs, unsigned int* flags)
{
    __shared__ float sRed[2][4 * 64 * RSTR];
    __shared__ float sBih[COLS];

    const int tid  = threadIdx.x;
    const int wg   = blockIdx.x;
    const int j0   = wg * COLS;
    const int w    = tid >> 6;
    const int lane = tid & 63;
    const int q    = lane >> 4;
    const int nn   = lane & 15;
    const int kb   = w * 512;   // this wave's k range in H
    const int xkb  = w * 32;    // this wave's k range in I

    if (tid < COLS) sBih[tid] = bih[j0 + tid];

    // Preload all W fragments into registers. B-frag for lane (q,nn):
    // W[j0+nn][kk + q*8 .. +8] - contiguous 16B, direct global b128 load.
    bf16x8 wh[16], wl[16], bxh, bxl;
    {
        const size_t wrow = (size_t)(j0 + nn) * H_ + (size_t)(kb + q * 8);
#pragma unroll
        for (int ks = 0; ks < 16; ++ks) {
            wh[ks] = *(const bf16x8*)&whi[wrow + ks * 32];
            wl[ks] = *(const bf16x8*)&wlo[wrow + ks * 32];
        }
        const size_t xrow = (size_t)(j0 + nn) * I_ + (size_t)(xkb + q * 8);
        bxh = *(const bf16x8*)&wihh[xrow];
        bxl = *(const bf16x8*)&wihl[xrow];
    }

#pragma unroll 1
    for (int t = 0; t < S_; ++t) {
        const unsigned short* hp = hs + (size_t)t * SLAB;
        floatx4 a0 = {0.f, 0.f, 0.f, 0.f}, a1 = a0, a2 = a0, a3 = a0;

        // h-independent x-projection first (overlaps producer latency)
        {
            const size_t xoff = (size_t)t * I_ + xkb + q * 8;
            bf16x8 x0 = *(const bf16x8*)&xbf[(size_t)(nn)      * (S_ * I_) + xoff];
            bf16x8 x1 = *(const bf16x8*)&xbf[(size_t)(16 + nn) * (S_ * I_) + xoff];
            bf16x8 x2 = *(const bf16x8*)&xbf[(size_t)(32 + nn) * (S_ * I_) + xoff];
            bf16x8 x3 = *(const bf16x8*)&xbf[(size_t)(48 + nn) * (S_ * I_) + xoff];
            a0 = __builtin_amdgcn_mfma_f32_16x16x32_bf16(x0, bxh, a0, 0, 0, 0);
            a1 = __builtin_amdgcn_mfma_f32_16x16x32_bf16(x1, bxh, a1, 0, 0, 0);
            a2 = __builtin_amdgcn_mfma_f32_16x16x32_bf16(x2, bxh, a2, 0, 0, 0);
            a3 = __builtin_amdgcn_mfma_f32_16x16x32_bf16(x3, bxh, a3, 0, 0, 0);
            a0 = __builtin_amdgcn_mfma_f32_16x16x32_bf16(x0, bxl, a0, 0, 0, 0);
            a1 = __builtin_amdgcn_mfma_f32_16x16x32_bf16(x1, bxl, a1, 0, 0, 0);
            a2 = __builtin_amdgcn_mfma_f32_16x16x32_bf16(x2, bxl, a2, 0, 0, 0);
            a3 = __builtin_amdgcn_mfma_f32_16x16x32_bf16(x3, bxl, a3, 0, 0, 0);
        }

        // wait for THIS WAVE's 32 producers of slab t (flag==4 => all 4
        // producer waves stored + acked). t=0 reads the memset zero slab.
        if (t > 0) {
            unsigned int* fl = flags + (size_t)(t - 1) * NWG + 32 * w;
            for (;;) {
                unsigned v = 4u;
                if (lane < 32)
                    v = __hip_atomic_load(&fl[lane], __ATOMIC_RELAXED,
                                          __HIP_MEMORY_SCOPE_AGENT);
                if (__ballot(v < 4u) == 0ull) break;
            }
        }

        // recurrent K-slice: 16 ks steps, W from registers, h from global
#pragma unroll
        for (int ks = 0; ks < 16; ++ks) {
            const int kk = kb + ks * 32 + q * 8;
            bf16x8 h0 = *(const bf16x8*)&hp[(size_t)(nn)      * H_ + kk];
            bf16x8 h1 = *(const bf16x8*)&hp[(size_t)(16 + nn) * H_ + kk];
            bf16x8 h2 = *(const bf16x8*)&hp[(size_t)(32 + nn) * H_ + kk];
            bf16x8 h3 = *(const bf16x8*)&hp[(size_t)(48 + nn) * H_ + kk];
            a0 = __builtin_amdgcn_mfma_f32_16x16x32_bf16(h0, wh[ks], a0, 0, 0, 0);
            a1 = __builtin_amdgcn_mfma_f32_16x16x32_bf16(h1, wh[ks], a1, 0, 0, 0);
            a2 = __builtin_amdgcn_mfma_f32_16x16x32_bf16(h2, wh[ks], a2, 0, 0, 0);
            a3 = __builtin_amdgcn_mfma_f32_16x16x32_bf16(h3, wh[ks], a3, 0, 0, 0);
            a0 = __builtin_amdgcn_mfma_f32_16x16x32_bf16(h0, wl[ks], a0, 0, 0, 0);
            a1 = __builtin_amdgcn_mfma_f32_16x16x32_bf16(h1, wl[ks], a1, 0, 0, 0);
            a2 = __builtin_amdgcn_mfma_f32_16x16x32_bf16(h2, wl[ks], a2, 0, 0, 0);
            a3 = __builtin_amdgcn_mfma_f32_16x16x32_bf16(h3, wl[ks], a3, 0, 0, 0);
        }

        // wave partials -> LDS (buffer t&1). row = w*64 + sub*16 + q*4+r
        float* sr = sRed[t & 1];
#pragma unroll
        for (int r = 0; r < 4; ++r) {
            sr[(w * 64 +      q * 4 + r) * RSTR + nn] = a0[r];
            sr[(w * 64 + 16 + q * 4 + r) * RSTR + nn] = a1[r];
            sr[(w * 64 + 32 + q * 4 + r) * RSTR + nn] = a2[r];
            sr[(w * 64 + 48 + q * 4 + r) * RSTR + nn] = a3[r];
        }
        __syncthreads();   // the ONE barrier per step

        // reduce 4 waves, +bih, tanh, pack bf16, agent-scope store h slice
        {
            const int m  = tid >> 2;          // batch index 0..63
            const int n0 = (tid & 3) * 4;     // local col 0,4,8,12
            floatx4 s = *(const floatx4*)&sr[(0 * 64 + m) * RSTR + n0];
            s += *(const floatx4*)&sr[(1 * 64 + m) * RSTR + n0];
            s += *(const floatx4*)&sr[(2 * 64 + m) * RSTR + n0];
            s += *(const floatx4*)&sr[(3 * 64 + m) * RSTR + n0];
            union { ushort4 u4; unsigned long long u64; } cv;
            cv.u4 = make_ushort4(
                f2bf(fast_tanh(s[0] + sBih[n0 + 0])),
                f2bf(fast_tanh(s[1] + sBih[n0 + 1])),
                f2bf(fast_tanh(s[2] + sBih[n0 + 2])),
                f2bf(fast_tanh(s[3] + sBih[n0 + 3])));
            unsigned long long* dst = (unsigned long long*)
                &hs[(size_t)(t + 1) * SLAB + (size_t)m * H_ + j0 + n0];
            __hip_atomic_store(dst, cv.u64, __ATOMIC_RELAXED, __HIP_MEMORY_SCOPE_AGENT);
        }

        // per-wave publish: drain own sc1 stores, then bump WG flag
        asm volatile("s_waitcnt vmcnt(0)" ::: "memory");
        if (lane == 0)
            __hip_atomic_fetch_add(&flags[(size_t)t * NWG + wg], 1u,
                                   __ATOMIC_RELAXED, __HIP_MEMORY_SCOPE_AGENT);
    }
}

// ---- output projection: out[b,t,o] = hs[t+1][b,:] . Who[o,:] + bho ------
__global__ __launch_bounds__(NTHREADS) void k_out(
    const unsigned short* __restrict__ hflat, const unsigned short* __restrict__ who,
    const float* __restrict__ bho, float* __restrict__ out)
{
    const int tid = threadIdx.x;
    const int w = tid >> 6, lane = tid & 63, q = lane >> 4, nn = lane & 15;
    const size_t r0 = ((size_t)blockIdx.x * 4 + w) * 16;   // row = t*64+b
    floatx4 acc[8];
#pragma unroll
    for (int i = 0; i < 8; ++i) acc[i] = floatx4{0.f, 0.f, 0.f, 0.f};
    for (int ks = 0; ks < 64; ++ks) {
        const int kk = ks * 32 + q * 8;
        bf16x8 a = *(const bf16x8*)&hflat[(r0 + nn) * H_ + kk];
#pragma unroll
        for (int nt = 0; nt < 8; ++nt) {
            bf16x8 b = *(const bf16x8*)&who[(size_t)(nt * 16 + nn) * H_ + kk];
            acc[nt] = __builtin_amdgcn_mfma_f32_16x16x32_bf16(a, b, acc[nt], 0, 0, 0);
        }
    }
#pragma unroll
    for (int nt = 0; nt < 8; ++nt) {
#pragma unroll
        for (int r = 0; r < 4; ++r) {
            size_t rr = r0 + q * 4 + r;
            int t = (int)(rr >> 6), b = (int)(rr & 63);
            int o = nt * 16 + nn;
            out[(size_t)b * (S_ * O_) + (size_t)t * O_ + o] = acc[nt][r] + bho[o];
        }
    }
}

// ---- host ----------------------------------------------------------------
extern "C" void kernel_launch(void* const* d_in, const int* in_sizes, int n_in,
                              void* d_out, int out_size, void* d_ws, size_t ws_size,
                              hipStream_t stream) {
    const float* x    = (const float*)d_in[0];
    const float* Wih  = (const float*)d_in[1];
    const float* bih  = (const float*)d_in[2];
    const float* Whh  = (const float*)d_in[3];
    const float* Who  = (const float*)d_in[4];
    const float* bho  = (const float*)d_in[5];
    const float* mask = (const float*)d_in[6];
    float* out = (float*)d_out;

    char* ws = (char*)d_ws;
    constexpr size_t FLAGS_OFF   = 0;                       // 512*128 u32
    constexpr size_t FLAGS_BYTES = (size_t)S_ * NWG * 4;
    constexpr size_t HS_OFF   = FLAGS_OFF + FLAGS_BYTES;
    constexpr size_t HS_BYTES = (size_t)(S_ + 1) * SLAB * 2;
    constexpr size_t WHI_OFF  = HS_OFF + HS_BYTES;
    constexpr size_t WLO_OFF  = WHI_OFF + (size_t)H_ * H_ * 2;
    constexpr size_t XBF_OFF  = WLO_OFF + (size_t)H_ * H_ * 2;
    constexpr size_t WIHH_OFF = XBF_OFF + (size_t)B_ * S_ * I_ * 2;
    constexpr size_t WIHL_OFF = WIHH_OFF + (size_t)H_ * I_ * 2;
    constexpr size_t WHO_OFF  = WIHL_OFF + (size_t)H_ * I_ * 2;
    constexpr size_t WS_NEED  = WHO_OFF + (size_t)O_ * H_ * 2;
    if (ws_size < WS_NEED) return;

    unsigned int*   flags = (unsigned int*)(ws + FLAGS_OFF);
    unsigned short* hs    = (unsigned short*)(ws + HS_OFF);
    unsigned short* whi   = (unsigned short*)(ws + WHI_OFF);
    unsigned short* wlo   = (unsigned short*)(ws + WLO_OFF);
    unsigned short* xbf   = (unsigned short*)(ws + XBF_OFF);
    unsigned short* wihh  = (unsigned short*)(ws + WIHH_OFF);
    unsigned short* wihl  = (unsigned short*)(ws + WIHL_OFF);
    unsigned short* whobf = (unsigned short*)(ws + WHO_OFF);

    hipMemsetAsync(flags, 0, FLAGS_BYTES, stream);        // flag slots
    hipMemsetAsync(hs, 0, (size_t)SLAB * 2, stream);      // h_{-1} = 0

    k_wsplit<<<1024, 256, 0, stream>>>(Whh, mask, whi, wlo, H_ * H_);
    k_split <<<256, 256, 0, stream>>>(Wih, wihh, wihl, H_ * I_);
    k_cast  <<<256, 256, 0, stream>>>(Who, whobf, O_ * H_);
    k_cast  <<<1024, 256, 0, stream>>>(x, xbf, B_ * S_ * I_);

    k_rnn<<<NWG, NTHREADS, 0, stream>>>(whi, wlo, wihh, wihl, xbf, bih, hs, flags);
    k_out<<<512, NTHREADS, 0, stream>>>(hs + SLAB, whobf, bho, out);
}

// Round 4
// 5050.094 us; speedup vs baseline: 2.1308x; 1.0078x over previous
//
#include <hip/hip_runtime.h>
#include <stdint.h>
#include <math.h>

#define B_ 64
#define S_ 512
#define I_ 128
#define H_ 2048
#define O_ 128
#define NWG 128
#define COLS 16
#define NTHREADS 256
#define SLAB (B_ * H_)      /* 131072 elements per h snapshot */
#define RSTR 20             /* sRed row stride in floats */
#define FSTR 32             /* flag stride in u32: one 128-B line per flag */

typedef __attribute__((ext_vector_type(8))) __bf16 bf16x8;
typedef __attribute__((ext_vector_type(4))) float floatx4;

__device__ __forceinline__ unsigned short f2bf(float f) {
    unsigned u = __float_as_uint(f);
    unsigned r = u + 0x7fffu + ((u >> 16) & 1u);   // RNE
    return (unsigned short)(r >> 16);
}
__device__ __forceinline__ float bf2f(unsigned short h) {
    return __uint_as_float(((unsigned)h) << 16);
}
// tanh(x) = 1 - 2/(e^{2x}+1); err ~1e-6 << bf16 noise.
__device__ __forceinline__ float fast_tanh(float x) {
    float e = __expf(2.0f * x);
    return 1.0f - 2.0f * __builtin_amdgcn_rcpf(e + 1.0f);
}

// ---- prep kernels -------------------------------------------------------
__global__ void k_wsplit(const float* __restrict__ whh, const float* __restrict__ mask,
                         unsigned short* __restrict__ hi, unsigned short* __restrict__ lo, int n) {
    int i = blockIdx.x * blockDim.x + threadIdx.x;
    int stride = gridDim.x * blockDim.x;
    for (; i < n; i += stride) {
        float w = whh[i] * mask[i];
        unsigned short h = f2bf(w);
        hi[i] = h;
        lo[i] = f2bf(w - bf2f(h));
    }
}
__global__ void k_split(const float* __restrict__ src,
                        unsigned short* __restrict__ hi, unsigned short* __restrict__ lo, int n) {
    int i = blockIdx.x * blockDim.x + threadIdx.x;
    int stride = gridDim.x * blockDim.x;
    for (; i < n; i += stride) {
        float w = src[i];
        unsigned short h = f2bf(w);
        hi[i] = h;
        lo[i] = f2bf(w - bf2f(h));
    }
}
__global__ void k_cast(const float* __restrict__ src, unsigned short* __restrict__ dst, int n) {
    int i = blockIdx.x * blockDim.x + threadIdx.x;
    int stride = gridDim.x * blockDim.x;
    for (; i < n; i += stride) dst[i] = f2bf(src[i]);
}

// ---- persistent recurrence kernel --------------------------------------
// 128 WGs x 256 thr; WG owns 16 output cols; split-K over 4 waves.
// Sync design (round 4): ZERO atomic RMWs, zero shared hot lines.
//  - publish: each wave sc1-stores its 16 rows of h(t+1), drains its own
//    vmcnt, then lane0 plain-stores the monotonic value (t+1) to the
//    wave's PRIVATE flag line (stride 128 B).
//  - consume: wave w needs producer WGs [32w,32w+32) x 4 waves = 128
//    flags = 128 distinct lines, polled with two 64-lane gather loads,
//    software-pipelined (next poll issued before checking current) so
//    detect ~ 1 MALL RT after the flag lands.
__global__ __launch_bounds__(NTHREADS, 1) void k_rnn(
    const unsigned short* __restrict__ whi, const unsigned short* __restrict__ wlo,
    const unsigned short* __restrict__ wihh, const unsigned short* __restrict__ wihl,
    const unsigned short* __restrict__ xbf, const float* __restrict__ bih,
    unsigned short* hs, unsigned int* flags)
{
    __shared__ float sRed[2][4 * 64 * RSTR];
    __shared__ float sBih[COLS];

    const int tid  = threadIdx.x;
    const int wg   = blockIdx.x;
    const int j0   = wg * COLS;
    const int w    = tid >> 6;
    const int lane = tid & 63;
    const int q    = lane >> 4;
    const int nn   = lane & 15;
    const int kb   = w * 512;   // this wave's k range in H
    const int xkb  = w * 32;    // this wave's k range in I

    if (tid < COLS) sBih[tid] = bih[j0 + tid];

    // This wave's private flag (one 128-B line), and its 128 producer flags
    unsigned int* const myflag = flags + (size_t)(wg * 4 + w) * FSTR;
    const unsigned int* const pf0 = flags + (size_t)(128 * w + lane) * FSTR;
    const unsigned int* const pf1 = pf0 + (size_t)64 * FSTR;

    // Preload W fragments (compiler may rematerialize from L2; off-chain)
    bf16x8 wh[16], wl[16], bxh, bxl;
    {
        const size_t wrow = (size_t)(j0 + nn) * H_ + (size_t)(kb + q * 8);
#pragma unroll
        for (int ks = 0; ks < 16; ++ks) {
            wh[ks] = *(const bf16x8*)&whi[wrow + ks * 32];
            wl[ks] = *(const bf16x8*)&wlo[wrow + ks * 32];
        }
        const size_t xrow = (size_t)(j0 + nn) * I_ + (size_t)(xkb + q * 8);
        bxh = *(const bf16x8*)&wihh[xrow];
        bxl = *(const bf16x8*)&wihl[xrow];
    }

#pragma unroll 1
    for (int t = 0; t < S_; ++t) {
        const unsigned short* hp = hs + (size_t)t * SLAB;
        floatx4 a0 = {0.f, 0.f, 0.f, 0.f}, a1 = a0, a2 = a0, a3 = a0;

        // h-independent x-projection first (overlaps producer latency)
        {
            const size_t xoff = (size_t)t * I_ + xkb + q * 8;
            bf16x8 x0 = *(const bf16x8*)&xbf[(size_t)(nn)      * (S_ * I_) + xoff];
            bf16x8 x1 = *(const bf16x8*)&xbf[(size_t)(16 + nn) * (S_ * I_) + xoff];
            bf16x8 x2 = *(const bf16x8*)&xbf[(size_t)(32 + nn) * (S_ * I_) + xoff];
            bf16x8 x3 = *(const bf16x8*)&xbf[(size_t)(48 + nn) * (S_ * I_) + xoff];
            a0 = __builtin_amdgcn_mfma_f32_16x16x32_bf16(x0, bxh, a0, 0, 0, 0);
            a1 = __builtin_amdgcn_mfma_f32_16x16x32_bf16(x1, bxh, a1, 0, 0, 0);
            a2 = __builtin_amdgcn_mfma_f32_16x16x32_bf16(x2, bxh, a2, 0, 0, 0);
            a3 = __builtin_amdgcn_mfma_f32_16x16x32_bf16(x3, bxh, a3, 0, 0, 0);
            a0 = __builtin_amdgcn_mfma_f32_16x16x32_bf16(x0, bxl, a0, 0, 0, 0);
            a1 = __builtin_amdgcn_mfma_f32_16x16x32_bf16(x1, bxl, a1, 0, 0, 0);
            a2 = __builtin_amdgcn_mfma_f32_16x16x32_bf16(x2, bxl, a2, 0, 0, 0);
            a3 = __builtin_amdgcn_mfma_f32_16x16x32_bf16(x3, bxl, a3, 0, 0, 0);
        }

        // wait for slab t: all 128 producer-wave flags must reach value t.
        // (flag value t was stored at the end of step t-1; monotonic, so
        // test v < t. t=0 reads the memset zero slab, no wait.)
        if (t > 0) {
            const unsigned want = (unsigned)t;
            unsigned va = __hip_atomic_load(pf0, __ATOMIC_RELAXED, __HIP_MEMORY_SCOPE_AGENT);
            unsigned vb = __hip_atomic_load(pf1, __ATOMIC_RELAXED, __HIP_MEMORY_SCOPE_AGENT);
            for (;;) {
                unsigned na = __hip_atomic_load(pf0, __ATOMIC_RELAXED, __HIP_MEMORY_SCOPE_AGENT);
                unsigned nb = __hip_atomic_load(pf1, __ATOMIC_RELAXED, __HIP_MEMORY_SCOPE_AGENT);
                if ((__ballot(va < want) | __ballot(vb < want)) == 0ull) break;
                va = na; vb = nb;
            }
        }

        // recurrent K-slice: 16 ks steps
#pragma unroll
        for (int ks = 0; ks < 16; ++ks) {
            const int kk = kb + ks * 32 + q * 8;
            bf16x8 h0 = *(const bf16x8*)&hp[(size_t)(nn)      * H_ + kk];
            bf16x8 h1 = *(const bf16x8*)&hp[(size_t)(16 + nn) * H_ + kk];
            bf16x8 h2 = *(const bf16x8*)&hp[(size_t)(32 + nn) * H_ + kk];
            bf16x8 h3 = *(const bf16x8*)&hp[(size_t)(48 + nn) * H_ + kk];
            a0 = __builtin_amdgcn_mfma_f32_16x16x32_bf16(h0, wh[ks], a0, 0, 0, 0);
            a1 = __builtin_amdgcn_mfma_f32_16x16x32_bf16(h1, wh[ks], a1, 0, 0, 0);
            a2 = __builtin_amdgcn_mfma_f32_16x16x32_bf16(h2, wh[ks], a2, 0, 0, 0);
            a3 = __builtin_amdgcn_mfma_f32_16x16x32_bf16(h3, wh[ks], a3, 0, 0, 0);
            a0 = __builtin_amdgcn_mfma_f32_16x16x32_bf16(h0, wl[ks], a0, 0, 0, 0);
            a1 = __builtin_amdgcn_mfma_f32_16x16x32_bf16(h1, wl[ks], a1, 0, 0, 0);
            a2 = __builtin_amdgcn_mfma_f32_16x16x32_bf16(h2, wl[ks], a2, 0, 0, 0);
            a3 = __builtin_amdgcn_mfma_f32_16x16x32_bf16(h3, wl[ks], a3, 0, 0, 0);
        }

        // wave partials -> LDS (buffer t&1)
        float* sr = sRed[t & 1];
#pragma unroll
        for (int r = 0; r < 4; ++r) {
            sr[(w * 64 +      q * 4 + r) * RSTR + nn] = a0[r];
            sr[(w * 64 + 16 + q * 4 + r) * RSTR + nn] = a1[r];
            sr[(w * 64 + 32 + q * 4 + r) * RSTR + nn] = a2[r];
            sr[(w * 64 + 48 + q * 4 + r) * RSTR + nn] = a3[r];
        }
        __syncthreads();   // the ONE barrier per step

        // reduce 4 waves, +bih, tanh, pack, sc1-store h slice.
        // wave w handles rows m in [16w, 16w+16): its flag certifies them.
        {
            const int m  = tid >> 2;          // batch row 0..63
            const int n0 = (tid & 3) * 4;     // local col 0,4,8,12
            floatx4 s = *(const floatx4*)&sr[(0 * 64 + m) * RSTR + n0];
            s += *(const floatx4*)&sr[(1 * 64 + m) * RSTR + n0];
            s += *(const floatx4*)&sr[(2 * 64 + m) * RSTR + n0];
            s += *(const floatx4*)&sr[(3 * 64 + m) * RSTR + n0];
            union { ushort4 u4; unsigned long long u64; } cv;
            cv.u4 = make_ushort4(
                f2bf(fast_tanh(s[0] + sBih[n0 + 0])),
                f2bf(fast_tanh(s[1] + sBih[n0 + 1])),
                f2bf(fast_tanh(s[2] + sBih[n0 + 2])),
                f2bf(fast_tanh(s[3] + sBih[n0 + 3])));
            unsigned long long* dst = (unsigned long long*)
                &hs[(size_t)(t + 1) * SLAB + (size_t)m * H_ + j0 + n0];
            __hip_atomic_store(dst, cv.u64, __ATOMIC_RELAXED, __HIP_MEMORY_SCOPE_AGENT);
        }

        // per-wave publish: drain own sc1 stores, then plain-store private
        // flag = t+1 (monotonic; no RMW, no shared line, no fence)
        asm volatile("s_waitcnt vmcnt(0)" ::: "memory");
        if (lane == 0)
            __hip_atomic_store(myflag, (unsigned)(t + 1),
                               __ATOMIC_RELAXED, __HIP_MEMORY_SCOPE_AGENT);
    }
}

// ---- output projection: out[b,t,o] = hs[t+1][b,:] . Who[o,:] + bho ------
__global__ __launch_bounds__(NTHREADS) void k_out(
    const unsigned short* __restrict__ hflat, const unsigned short* __restrict__ who,
    const float* __restrict__ bho, float* __restrict__ out)
{
    const int tid = threadIdx.x;
    const int w = tid >> 6, lane = tid & 63, q = lane >> 4, nn = lane & 15;
    const size_t r0 = ((size_t)blockIdx.x * 4 + w) * 16;   // row = t*64+b
    floatx4 acc[8];
#pragma unroll
    for (int i = 0; i < 8; ++i) acc[i] = floatx4{0.f, 0.f, 0.f, 0.f};
    for (int ks = 0; ks < 64; ++ks) {
        const int kk = ks * 32 + q * 8;
        bf16x8 a = *(const bf16x8*)&hflat[(r0 + nn) * H_ + kk];
#pragma unroll
        for (int nt = 0; nt < 8; ++nt) {
            bf16x8 b = *(const bf16x8*)&who[(size_t)(nt * 16 + nn) * H_ + kk];
            acc[nt] = __builtin_amdgcn_mfma_f32_16x16x32_bf16(a, b, acc[nt], 0, 0, 0);
        }
    }
#pragma unroll
    for (int nt = 0; nt < 8; ++nt) {
#pragma unroll
        for (int r = 0; r < 4; ++r) {
            size_t rr = r0 + q * 4 + r;
            int t = (int)(rr >> 6), b = (int)(rr & 63);
            int o = nt * 16 + nn;
            out[(size_t)b * (S_ * O_) + (size_t)t * O_ + o] = acc[nt][r] + bho[o];
        }
    }
}

// ---- host ----------------------------------------------------------------
extern "C" void kernel_launch(void* const* d_in, const int* in_sizes, int n_in,
                              void* d_out, int out_size, void* d_ws, size_t ws_size,
                              hipStream_t stream) {
    const float* x    = (const float*)d_in[0];
    const float* Wih  = (const float*)d_in[1];
    const float* bih  = (const float*)d_in[2];
    const float* Whh  = (const float*)d_in[3];
    const float* Who  = (const float*)d_in[4];
    const float* bho  = (const float*)d_in[5];
    const float* mask = (const float*)d_in[6];
    float* out = (float*)d_out;

    char* ws = (char*)d_ws;
    constexpr size_t FLAGS_OFF   = 0;   // 512 waves * 128-B line = 64 KB
    constexpr size_t FLAGS_BYTES = (size_t)NWG * 4 * FSTR * 4;
    constexpr size_t HS_OFF   = FLAGS_OFF + FLAGS_BYTES;
    constexpr size_t HS_BYTES = (size_t)(S_ + 1) * SLAB * 2;
    constexpr size_t WHI_OFF  = HS_OFF + HS_BYTES;
    constexpr size_t WLO_OFF  = WHI_OFF + (size_t)H_ * H_ * 2;
    constexpr size_t XBF_OFF  = WLO_OFF + (size_t)H_ * H_ * 2;
    constexpr size_t WIHH_OFF = XBF_OFF + (size_t)B_ * S_ * I_ * 2;
    constexpr size_t WIHL_OFF = WIHH_OFF + (size_t)H_ * I_ * 2;
    constexpr size_t WHO_OFF  = WIHL_OFF + (size_t)H_ * I_ * 2;
    constexpr size_t WS_NEED  = WHO_OFF + (size_t)O_ * H_ * 2;
    if (ws_size < WS_NEED) return;

    unsigned int*   flags = (unsigned int*)(ws + FLAGS_OFF);
    unsigned short* hs    = (unsigned short*)(ws + HS_OFF);
    unsigned short* whi   = (unsigned short*)(ws + WHI_OFF);
    unsigned short* wlo   = (unsigned short*)(ws + WLO_OFF);
    unsigned short* xbf   = (unsigned short*)(ws + XBF_OFF);
    unsigned short* wihh  = (unsigned short*)(ws + WIHH_OFF);
    unsigned short* wihl  = (unsigned short*)(ws + WIHL_OFF);
    unsigned short* whobf = (unsigned short*)(ws + WHO_OFF);

    hipMemsetAsync(flags, 0, FLAGS_BYTES, stream);        // flag lines = 0
    hipMemsetAsync(hs, 0, (size_t)SLAB * 2, stream);      // h_{-1} = 0

    k_wsplit<<<1024, 256, 0, stream>>>(Whh, mask, whi, wlo, H_ * H_);
    k_split <<<256, 256, 0, stream>>>(Wih, wihh, wihl, H_ * I_);
    k_cast  <<<256, 256, 0, stream>>>(Who, whobf, O_ * H_);
    k_cast  <<<1024, 256, 0, stream>>>(x, xbf, B_ * S_ * I_);

    k_rnn<<<NWG, NTHREADS, 0, stream>>>(whi, wlo, wihh, wihl, xbf, bih, hs, flags);
    k_out<<<512, NTHREADS, 0, stream>>>(hs + SLAB, whobf, bho, out);
}

// Round 5
// 4927.238 us; speedup vs baseline: 2.1839x; 1.0249x over previous
//
#include <hip/hip_runtime.h>
#include <stdint.h>
#include <math.h>

#define B_ 64
#define S_ 512
#define I_ 128
#define H_ 2048
#define O_ 128
#define NWG 128
#define COLS 16
#define NTHREADS 256
#define SLAB (B_ * H_)      /* 131072 elements per h snapshot */
#define RSTR 20             /* sRed row stride in floats */

typedef __attribute__((ext_vector_type(8))) __bf16 bf16x8;
typedef __attribute__((ext_vector_type(4))) float floatx4;
typedef __attribute__((ext_vector_type(4))) unsigned int uintx4;

__device__ __forceinline__ unsigned short f2bf(float f) {
    unsigned u = __float_as_uint(f);
    unsigned r = u + 0x7fffu + ((u >> 16) & 1u);   // RNE
    return (unsigned short)(r >> 16);
}
__device__ __forceinline__ float bf2f(unsigned short h) {
    return __uint_as_float(((unsigned)h) << 16);
}
// tanh(x) = 1 - 2/(e^{2x}+1); err ~1e-6 << bf16 noise.
__device__ __forceinline__ float fast_tanh(float x) {
    float e = __expf(2.0f * x);
    return 1.0f - 2.0f * __builtin_amdgcn_rcpf(e + 1.0f);
}

// ---- prep kernels -------------------------------------------------------
__global__ void k_wsplit(const float* __restrict__ whh, const float* __restrict__ mask,
                         unsigned short* __restrict__ hi, unsigned short* __restrict__ lo, int n) {
    int i = blockIdx.x * blockDim.x + threadIdx.x;
    int stride = gridDim.x * blockDim.x;
    for (; i < n; i += stride) {
        float w = whh[i] * mask[i];
        unsigned short h = f2bf(w);
        hi[i] = h;
        lo[i] = f2bf(w - bf2f(h));
    }
}
__global__ void k_split(const float* __restrict__ src,
                        unsigned short* __restrict__ hi, unsigned short* __restrict__ lo, int n) {
    int i = blockIdx.x * blockDim.x + threadIdx.x;
    int stride = gridDim.x * blockDim.x;
    for (; i < n; i += stride) {
        float w = src[i];
        unsigned short h = f2bf(w);
        hi[i] = h;
        lo[i] = f2bf(w - bf2f(h));
    }
}
__global__ void k_cast(const float* __restrict__ src, unsigned short* __restrict__ dst, int n) {
    int i = blockIdx.x * blockDim.x + threadIdx.x;
    int stride = gridDim.x * blockDim.x;
    for (; i < n; i += stride) dst[i] = f2bf(src[i]);
}

// ---- persistent recurrence kernel --------------------------------------
// 128 WGs x 256 thr; WG owns 16 output cols; split-K over 4 waves.
// Round-5 sync: MINIMAL fabric traffic.
//  - publish: 128 threads sc1-store 16 B each (dwordx4, write-through to
//    coherence point), all waves drain vmcnt, __syncthreads, then tid0
//    plain-stores monotonic (t+1) to flags[wg]. ONE flag per WG.
//  - consume: wave w needs producer WGs [32w,32w+32) -> flags[32w..32w+32)
//    = ONE 128-B line; polled with a single dword load per lane + ballot.
//    4 hot lines total on the whole GPU (was 512 lines x 128 probes).
__global__ __launch_bounds__(NTHREADS, 1) void k_rnn(
    const unsigned short* __restrict__ whi, const unsigned short* __restrict__ wlo,
    const unsigned short* __restrict__ wihh, const unsigned short* __restrict__ wihl,
    const unsigned short* __restrict__ xbf, const float* __restrict__ bih,
    unsigned short* hs, unsigned int* flags)
{
    __shared__ float sRed[2][4 * 64 * RSTR];
    __shared__ float sBih[COLS];

    const int tid  = threadIdx.x;
    const int wg   = blockIdx.x;
    const int j0   = wg * COLS;
    const int w    = tid >> 6;
    const int lane = tid & 63;
    const int q    = lane >> 4;
    const int nn   = lane & 15;
    const int kb   = w * 512;   // this wave's k range in H
    const int xkb  = w * 32;    // this wave's k range in I

    if (tid < COLS) sBih[tid] = bih[j0 + tid];

    // consumer-wave poll target: one word of line w
    const unsigned int* const fpoll = flags + 32 * w + (lane & 31);

    // Preload W fragments (compiler may rematerialize from L2; off-chain)
    bf16x8 wh[16], wl[16], bxh, bxl;
    {
        const size_t wrow = (size_t)(j0 + nn) * H_ + (size_t)(kb + q * 8);
#pragma unroll
        for (int ks = 0; ks < 16; ++ks) {
            wh[ks] = *(const bf16x8*)&whi[wrow + ks * 32];
            wl[ks] = *(const bf16x8*)&wlo[wrow + ks * 32];
        }
        const size_t xrow = (size_t)(j0 + nn) * I_ + (size_t)(xkb + q * 8);
        bxh = *(const bf16x8*)&wihh[xrow];
        bxl = *(const bf16x8*)&wihl[xrow];
    }

#pragma unroll 1
    for (int t = 0; t < S_; ++t) {
        const unsigned short* hp = hs + (size_t)t * SLAB;
        floatx4 a0 = {0.f, 0.f, 0.f, 0.f}, a1 = a0, a2 = a0, a3 = a0;

        // h-independent x-projection first (overlaps producer latency)
        {
            const size_t xoff = (size_t)t * I_ + xkb + q * 8;
            bf16x8 x0 = *(const bf16x8*)&xbf[(size_t)(nn)      * (S_ * I_) + xoff];
            bf16x8 x1 = *(const bf16x8*)&xbf[(size_t)(16 + nn) * (S_ * I_) + xoff];
            bf16x8 x2 = *(const bf16x8*)&xbf[(size_t)(32 + nn) * (S_ * I_) + xoff];
            bf16x8 x3 = *(const bf16x8*)&xbf[(size_t)(48 + nn) * (S_ * I_) + xoff];
            a0 = __builtin_amdgcn_mfma_f32_16x16x32_bf16(x0, bxh, a0, 0, 0, 0);
            a1 = __builtin_amdgcn_mfma_f32_16x16x32_bf16(x1, bxh, a1, 0, 0, 0);
            a2 = __builtin_amdgcn_mfma_f32_16x16x32_bf16(x2, bxh, a2, 0, 0, 0);
            a3 = __builtin_amdgcn_mfma_f32_16x16x32_bf16(x3, bxh, a3, 0, 0, 0);
            a0 = __builtin_amdgcn_mfma_f32_16x16x32_bf16(x0, bxl, a0, 0, 0, 0);
            a1 = __builtin_amdgcn_mfma_f32_16x16x32_bf16(x1, bxl, a1, 0, 0, 0);
            a2 = __builtin_amdgcn_mfma_f32_16x16x32_bf16(x2, bxl, a2, 0, 0, 0);
            a3 = __builtin_amdgcn_mfma_f32_16x16x32_bf16(x3, bxl, a3, 0, 0, 0);
        }

        // wait for slab t: the 32 producer WGs of this wave's K-slice must
        // have published value >= t (stored as t at end of step t-1).
        if (t > 0) {
            const unsigned want = (unsigned)t;
            unsigned v;
            do {
                v = __hip_atomic_load(fpoll, __ATOMIC_RELAXED,
                                      __HIP_MEMORY_SCOPE_AGENT);
            } while (__ballot(v < want) != 0ull);
        }

        // recurrent K-slice: 16 ks steps
#pragma unroll
        for (int ks = 0; ks < 16; ++ks) {
            const int kk = kb + ks * 32 + q * 8;
            bf16x8 h0 = *(const bf16x8*)&hp[(size_t)(nn)      * H_ + kk];
            bf16x8 h1 = *(const bf16x8*)&hp[(size_t)(16 + nn) * H_ + kk];
            bf16x8 h2 = *(const bf16x8*)&hp[(size_t)(32 + nn) * H_ + kk];
            bf16x8 h3 = *(const bf16x8*)&hp[(size_t)(48 + nn) * H_ + kk];
            a0 = __builtin_amdgcn_mfma_f32_16x16x32_bf16(h0, wh[ks], a0, 0, 0, 0);
            a1 = __builtin_amdgcn_mfma_f32_16x16x32_bf16(h1, wh[ks], a1, 0, 0, 0);
            a2 = __builtin_amdgcn_mfma_f32_16x16x32_bf16(h2, wh[ks], a2, 0, 0, 0);
            a3 = __builtin_amdgcn_mfma_f32_16x16x32_bf16(h3, wh[ks], a3, 0, 0, 0);
            a0 = __builtin_amdgcn_mfma_f32_16x16x32_bf16(h0, wl[ks], a0, 0, 0, 0);
            a1 = __builtin_amdgcn_mfma_f32_16x16x32_bf16(h1, wl[ks], a1, 0, 0, 0);
            a2 = __builtin_amdgcn_mfma_f32_16x16x32_bf16(h2, wl[ks], a2, 0, 0, 0);
            a3 = __builtin_amdgcn_mfma_f32_16x16x32_bf16(h3, wl[ks], a3, 0, 0, 0);
        }

        // wave partials -> LDS (buffer t&1)
        float* sr = sRed[t & 1];
#pragma unroll
        for (int r = 0; r < 4; ++r) {
            sr[(w * 64 +      q * 4 + r) * RSTR + nn] = a0[r];
            sr[(w * 64 + 16 + q * 4 + r) * RSTR + nn] = a1[r];
            sr[(w * 64 + 32 + q * 4 + r) * RSTR + nn] = a2[r];
            sr[(w * 64 + 48 + q * 4 + r) * RSTR + nn] = a3[r];
        }
        __syncthreads();   // sRed ready

        // reduce 4 waves, +bih, tanh, pack bf16, ONE 16-B sc1 store per
        // thread (128 active threads: m = tid>>1, 8 cols each)
        if (tid < 128) {
            const int m  = tid >> 1;
            const int n0 = (tid & 1) * 8;
            floatx4 sA = *(const floatx4*)&sr[(0 * 64 + m) * RSTR + n0];
            floatx4 sB = *(const floatx4*)&sr[(0 * 64 + m) * RSTR + n0 + 4];
            sA += *(const floatx4*)&sr[(1 * 64 + m) * RSTR + n0];
            sB += *(const floatx4*)&sr[(1 * 64 + m) * RSTR + n0 + 4];
            sA += *(const floatx4*)&sr[(2 * 64 + m) * RSTR + n0];
            sB += *(const floatx4*)&sr[(2 * 64 + m) * RSTR + n0 + 4];
            sA += *(const floatx4*)&sr[(3 * 64 + m) * RSTR + n0];
            sB += *(const floatx4*)&sr[(3 * 64 + m) * RSTR + n0 + 4];
            union { unsigned short u[8]; uintx4 q; } cv;
#pragma unroll
            for (int j = 0; j < 4; ++j) {
                cv.u[j]     = f2bf(fast_tanh(sA[j] + sBih[n0 + j]));
                cv.u[4 + j] = f2bf(fast_tanh(sB[j] + sBih[n0 + 4 + j]));
            }
            unsigned short* dst =
                &hs[(size_t)(t + 1) * SLAB + (size_t)m * H_ + j0 + n0];
            // 16-B write-through to coherence point (agent-visible)
            asm volatile("global_store_dwordx4 %0, %1, off sc1"
                         :: "v"(dst), "v"(cv.q) : "memory");
        }

        // all waves drain their stores, then one flag store per WG
        asm volatile("s_waitcnt vmcnt(0)" ::: "memory");
        __syncthreads();
        if (tid == 0)
            __hip_atomic_store(&flags[wg], (unsigned)(t + 1),
                               __ATOMIC_RELAXED, __HIP_MEMORY_SCOPE_AGENT);
    }
}

// ---- output projection: out[b,t,o] = hs[t+1][b,:] . Who[o,:] + bho ------
__global__ __launch_bounds__(NTHREADS) void k_out(
    const unsigned short* __restrict__ hflat, const unsigned short* __restrict__ who,
    const float* __restrict__ bho, float* __restrict__ out)
{
    const int tid = threadIdx.x;
    const int w = tid >> 6, lane = tid & 63, q = lane >> 4, nn = lane & 15;
    const size_t r0 = ((size_t)blockIdx.x * 4 + w) * 16;   // row = t*64+b
    floatx4 acc[8];
#pragma unroll
    for (int i = 0; i < 8; ++i) acc[i] = floatx4{0.f, 0.f, 0.f, 0.f};
    for (int ks = 0; ks < 64; ++ks) {
        const int kk = ks * 32 + q * 8;
        bf16x8 a = *(const bf16x8*)&hflat[(r0 + nn) * H_ + kk];
#pragma unroll
        for (int nt = 0; nt < 8; ++nt) {
            bf16x8 b = *(const bf16x8*)&who[(size_t)(nt * 16 + nn) * H_ + kk];
            acc[nt] = __builtin_amdgcn_mfma_f32_16x16x32_bf16(a, b, acc[nt], 0, 0, 0);
        }
    }
#pragma unroll
    for (int nt = 0; nt < 8; ++nt) {
#pragma unroll
        for (int r = 0; r < 4; ++r) {
            size_t rr = r0 + q * 4 + r;
            int t = (int)(rr >> 6), b = (int)(rr & 63);
            int o = nt * 16 + nn;
            out[(size_t)b * (S_ * O_) + (size_t)t * O_ + o] = acc[nt][r] + bho[o];
        }
    }
}

// ---- host ----------------------------------------------------------------
extern "C" void kernel_launch(void* const* d_in, const int* in_sizes, int n_in,
                              void* d_out, int out_size, void* d_ws, size_t ws_size,
                              hipStream_t stream) {
    const float* x    = (const float*)d_in[0];
    const float* Wih  = (const float*)d_in[1];
    const float* bih  = (const float*)d_in[2];
    const float* Whh  = (const float*)d_in[3];
    const float* Who  = (const float*)d_in[4];
    const float* bho  = (const float*)d_in[5];
    const float* mask = (const float*)d_in[6];
    float* out = (float*)d_out;

    char* ws = (char*)d_ws;
    constexpr size_t FLAGS_OFF   = 0;       // 128 u32 packed in 4 lines
    constexpr size_t FLAGS_BYTES = 4096;
    constexpr size_t HS_OFF   = FLAGS_OFF + FLAGS_BYTES;
    constexpr size_t HS_BYTES = (size_t)(S_ + 1) * SLAB * 2;
    constexpr size_t WHI_OFF  = HS_OFF + HS_BYTES;
    constexpr size_t WLO_OFF  = WHI_OFF + (size_t)H_ * H_ * 2;
    constexpr size_t XBF_OFF  = WLO_OFF + (size_t)H_ * H_ * 2;
    constexpr size_t WIHH_OFF = XBF_OFF + (size_t)B_ * S_ * I_ * 2;
    constexpr size_t WIHL_OFF = WIHH_OFF + (size_t)H_ * I_ * 2;
    constexpr size_t WHO_OFF  = WIHL_OFF + (size_t)H_ * I_ * 2;
    constexpr size_t WS_NEED  = WHO_OFF + (size_t)O_ * H_ * 2;
    if (ws_size < WS_NEED) return;

    unsigned int*   flags = (unsigned int*)(ws + FLAGS_OFF);
    unsigned short* hs    = (unsigned short*)(ws + HS_OFF);
    unsigned short* whi   = (unsigned short*)(ws + WHI_OFF);
    unsigned short* wlo   = (unsigned short*)(ws + WLO_OFF);
    unsigned short* xbf   = (unsigned short*)(ws + XBF_OFF);
    unsigned short* wihh  = (unsigned short*)(ws + WIHH_OFF);
    unsigned short* wihl  = (unsigned short*)(ws + WIHL_OFF);
    unsigned short* whobf = (unsigned short*)(ws + WHO_OFF);

    hipMemsetAsync(flags, 0, FLAGS_BYTES, stream);        // flag lines = 0
    hipMemsetAsync(hs, 0, (size_t)SLAB * 2, stream);      // h_{-1} = 0

    k_wsplit<<<1024, 256, 0, stream>>>(Whh, mask, whi, wlo, H_ * H_);
    k_split <<<256, 256, 0, stream>>>(Wih, wihh, wihl, H_ * I_);
    k_cast  <<<256, 256, 0, stream>>>(Who, whobf, O_ * H_);
    k_cast  <<<1024, 256, 0, stream>>>(x, xbf, B_ * S_ * I_);

    k_rnn<<<NWG, NTHREADS, 0, stream>>>(whi, wlo, wihh, wihl, xbf, bih, hs, flags);
    k_out<<<512, NTHREADS, 0, stream>>>(hs + SLAB, whobf, bho, out);
}